// Round 2
// baseline (1412.012 us; speedup 1.0000x reference)
//
#include <hip/hip_runtime.h>
#include <hip/hip_bf16.h>
#include <stdint.h>

#define N_NODES 50000
#define N_EDGES 800000

typedef __attribute__((ext_vector_type(8))) short short8;
typedef __attribute__((ext_vector_type(4))) float floatx4;

__device__ __forceinline__ float bfbits2f(unsigned int u16) {
    union { unsigned int i; float f; } c; c.i = u16 << 16; return c.f;
}
__device__ __forceinline__ unsigned short f2bfbits(float f) {
    union { float f; unsigned int i; } c; c.f = f;
    unsigned int r = c.i + 0x7fffu + ((c.i >> 16) & 1u);   // RNE
    return (unsigned short)(r >> 16);
}

// ---------------- dtype detection (1 block) ----------------
// flags[0]: 1 if float inputs/outputs are fp32, 0 if bf16
// flags[1]: 1 if edge arrays are int64, 0 if int32
__global__ __launch_bounds__(256) void detect(
    const unsigned short* __restrict__ x16, const int* __restrict__ e,
    int* __restrict__ flags)
{
    __shared__ int s_cnt[2];
    const int t = threadIdx.x;
    if (t < 2) s_cnt[t] = 0;
    __syncthreads();
    // even-indexed shorts: bf16 values (sane exp) vs fp32 low-mantissa (noise)
    unsigned short v = x16[2 * t];
    int ex = (v >> 7) & 0xff;
    if (v == 0 || (ex >= 96 && ex <= 150)) atomicAdd(&s_cnt[0], 1);
    // odd int32s: int64 high words (==0) vs int32 src values (!=0 w.h.p.)
    if (e[2 * t + 1] != 0) atomicAdd(&s_cnt[1], 1);
    __syncthreads();
    if (t == 0) {
        flags[0] = (s_cnt[0] < 200) ? 1 : 0;
        flags[1] = (s_cnt[1] < 128) ? 1 : 0;
    }
}

// ---------------- weight prep: W[K,N] (bf16 or fp32) -> WT[N,K] bf16 ----------------
__global__ __launch_bounds__(256) void prep_w(
    const void* __restrict__ W, unsigned short* __restrict__ WT,
    int K, int Nout, const int* __restrict__ flags)
{
    int idx = blockIdx.x * 256 + threadIdx.x;
    if (idx >= K * Nout) return;
    int k = idx / Nout, n = idx - k * Nout;
    unsigned short v = flags[0] ? f2bfbits(((const float*)W)[idx])
                                : ((const unsigned short*)W)[idx];
    WT[n * K + k] = v;
}

__global__ __launch_bounds__(256) void prep_vec(
    const void* __restrict__ b, unsigned short* __restrict__ bb,
    int n, const int* __restrict__ flags)
{
    int i = blockIdx.x * 256 + threadIdx.x;
    if (i >= n) return;
    bb[i] = flags[0] ? f2bfbits(((const float*)b)[i]) : ((const unsigned short*)b)[i];
}

// ---------------- CSR build ----------------
__global__ __launch_bounds__(256) void zero_two(int* __restrict__ a, int* __restrict__ b, int n) {
    int i = blockIdx.x * 256 + threadIdx.x;
    if (i < n) { a[i] = 0; b[i] = 0; }
}

__global__ __launch_bounds__(256) void edge_count(
    const int* __restrict__ e, int* __restrict__ cnt, const int* __restrict__ flags)
{
    int i = blockIdx.x * 256 + threadIdx.x;
    if (i >= N_EDGES) return;
    int dst = flags[1] ? e[2 * (N_EDGES + i)] : e[N_EDGES + i];
    atomicAdd(&cnt[dst], 1);
}

__global__ __launch_bounds__(256) void scan_rowptr(
    const int* __restrict__ cnt, int* __restrict__ rowptr)
{
    __shared__ int sa[256], sb[256];
    const int t = threadIdx.x;
    int run = 0;
    for (int j = 0; j < N_NODES; j += 256) {
        const int idx = j + t;
        int v = (idx < N_NODES) ? cnt[idx] : 0;
        sa[t] = v;
        __syncthreads();
        bool par = true;                    // true: current data in sa
#pragma unroll
        for (int off = 1; off < 256; off <<= 1) {
            if (par) { int x = sa[t] + (t >= off ? sa[t - off] : 0); sb[t] = x; }
            else     { int x = sb[t] + (t >= off ? sb[t - off] : 0); sa[t] = x; }
            par = !par;
            __syncthreads();
        }
        int incl = sa[t];                   // 8 steps -> final back in sa
        int total = sa[255];
        if (idx < N_NODES) rowptr[idx] = run + incl - v;   // exclusive scan
        run += total;
        __syncthreads();
    }
}

__global__ __launch_bounds__(256) void edge_fill(
    const int* __restrict__ e, const int* __restrict__ rowptr,
    int* __restrict__ cursor, int* __restrict__ csr, const int* __restrict__ flags)
{
    int i = blockIdx.x * 256 + threadIdx.x;
    if (i >= N_EDGES) return;
    int f = flags[1];
    int src = f ? e[2 * i] : e[i];
    int dst = f ? e[2 * (N_EDGES + i)] : e[N_EDGES + i];
    int pos = atomicAdd(&cursor[dst], 1);
    csr[rowptr[dst] + pos] = src;
}

// ---------------- fused layer: CSR mean-aggregate + dual GEMM + bias + relu ----------------
// block = 256 threads (4 waves), handles a 16-node m-tile.
template<int K, int NOUT, bool FINAL>
__global__ __launch_bounds__(256) void sage_fused(
    const void* __restrict__ hin,             // [N,K] bf16 (or fp32 if layer0&&flag)
    const int* __restrict__ rowptr,
    const int* __restrict__ cnt,
    const int* __restrict__ csr_src,
    const unsigned short* __restrict__ WlT,   // [NOUT,K] bf16
    const unsigned short* __restrict__ WrT,   // [NOUT,K] bf16
    const unsigned short* __restrict__ bb,    // [NOUT] bf16
    void* __restrict__ hout,                  // [N,NOUT] bf16 (or fp32 if FINAL&&flag)
    const int* __restrict__ flags,
    int layer0)
{
    __shared__ unsigned short A0s[16][K + 8];
    const int wave = threadIdx.x >> 6;
    const int lane = threadIdx.x & 63;
    const int m0 = blockIdx.x * 16;
    const int fp32in = layer0 ? flags[0] : 0;
    constexpr int V = K / 64;                 // bf16 per lane per row (2 or 4)

    // ---- phase 1: each wave mean-aggregates 4 nodes into LDS ----
    for (int i = 0; i < 4; ++i) {
        const int node = m0 + wave * 4 + i;
        const int beg = rowptr[node];
        const int deg = cnt[node];
        float accA[V], accB[V];
#pragma unroll
        for (int v = 0; v < V; ++v) { accA[v] = 0.f; accB[v] = 0.f; }
        int j = 0;
        if (!fp32in) {
            const unsigned short* base = (const unsigned short*)hin;
            for (; j + 1 < deg; j += 2) {
                int s0 = csr_src[beg + j], s1 = csr_src[beg + j + 1];
                if (V == 2) {
                    unsigned int r0 = *(const unsigned int*)(base + (size_t)s0 * K + lane * 2);
                    unsigned int r1 = *(const unsigned int*)(base + (size_t)s1 * K + lane * 2);
                    accA[0] += bfbits2f(r0 & 0xffffu); accA[1] += bfbits2f(r0 >> 16);
                    accB[0] += bfbits2f(r1 & 0xffffu); accB[1] += bfbits2f(r1 >> 16);
                } else {
                    uint2 r0 = *(const uint2*)(base + (size_t)s0 * K + lane * 4);
                    uint2 r1 = *(const uint2*)(base + (size_t)s1 * K + lane * 4);
                    accA[0] += bfbits2f(r0.x & 0xffffu); accA[1] += bfbits2f(r0.x >> 16);
                    accA[2] += bfbits2f(r0.y & 0xffffu); accA[3] += bfbits2f(r0.y >> 16);
                    accB[0] += bfbits2f(r1.x & 0xffffu); accB[1] += bfbits2f(r1.x >> 16);
                    accB[2] += bfbits2f(r1.y & 0xffffu); accB[3] += bfbits2f(r1.y >> 16);
                }
            }
            if (j < deg) {
                int s0 = csr_src[beg + j];
                if (V == 2) {
                    unsigned int r0 = *(const unsigned int*)(base + (size_t)s0 * K + lane * 2);
                    accA[0] += bfbits2f(r0 & 0xffffu); accA[1] += bfbits2f(r0 >> 16);
                } else {
                    uint2 r0 = *(const uint2*)(base + (size_t)s0 * K + lane * 4);
                    accA[0] += bfbits2f(r0.x & 0xffffu); accA[1] += bfbits2f(r0.x >> 16);
                    accA[2] += bfbits2f(r0.y & 0xffffu); accA[3] += bfbits2f(r0.y >> 16);
                }
            }
        } else {
            // layer 0 only, K=128, fp32 features
            const float* base = (const float*)hin;
            for (; j < deg; ++j) {
                int s0 = csr_src[beg + j];
                float2 r0 = *(const float2*)(base + (size_t)s0 * K + lane * 2);
                accA[0] += r0.x; accA[1] += r0.y;
            }
        }
        float inv = 1.0f / fmaxf((float)deg, 1.0f);
#pragma unroll
        for (int v = 0; v < V; ++v)
            A0s[wave * 4 + i][lane * V + v] = f2bfbits((accA[v] + accB[v]) * inv);
    }
    __syncthreads();

    // ---- phase 2: MFMA dual GEMM ----
    const int r = lane & 15;
    const int quad = lane >> 4;
    short8 a0f[K / 32], a1f[K / 32];
#pragma unroll
    for (int k0 = 0; k0 < K / 32; ++k0)
        a0f[k0] = *(const short8*)&A0s[r][k0 * 32 + quad * 8];
    if (!fp32in) {
        const unsigned short* hb = (const unsigned short*)hin + (size_t)(m0 + r) * K + quad * 8;
#pragma unroll
        for (int k0 = 0; k0 < K / 32; ++k0)
            a1f[k0] = *(const short8*)(hb + k0 * 32);
    } else {
        const float* hf = (const float*)hin + (size_t)(m0 + r) * K + quad * 8;
#pragma unroll
        for (int k0 = 0; k0 < K / 32; ++k0) {
            floatx4 a = *(const floatx4*)(hf + k0 * 32);
            floatx4 b = *(const floatx4*)(hf + k0 * 32 + 4);
            short8 t;
            t[0] = (short)f2bfbits(a.x); t[1] = (short)f2bfbits(a.y);
            t[2] = (short)f2bfbits(a.z); t[3] = (short)f2bfbits(a.w);
            t[4] = (short)f2bfbits(b.x); t[5] = (short)f2bfbits(b.y);
            t[6] = (short)f2bfbits(b.z); t[7] = (short)f2bfbits(b.w);
            a1f[k0] = t;
        }
    }
    const int fp32out = FINAL ? flags[0] : 0;

    for (int nt = wave; nt < NOUT / 16; nt += 4) {
        const int n0 = nt * 16;
        floatx4 acc = {0.f, 0.f, 0.f, 0.f};
        const unsigned short* b0 = WlT + (size_t)(n0 + r) * K + quad * 8;
        const unsigned short* b1 = WrT + (size_t)(n0 + r) * K + quad * 8;
#pragma unroll
        for (int k0 = 0; k0 < K / 32; ++k0)
            acc = __builtin_amdgcn_mfma_f32_16x16x32_bf16(a0f[k0], *(const short8*)(b0 + k0 * 32), acc, 0, 0, 0);
#pragma unroll
        for (int k0 = 0; k0 < K / 32; ++k0)
            acc = __builtin_amdgcn_mfma_f32_16x16x32_bf16(a1f[k0], *(const short8*)(b1 + k0 * 32), acc, 0, 0, 0);

        // C/D layout: col = lane&15, row = quad*4 + reg  [HW-verified]
        const int ccol = n0 + r;
        float bv = bfbits2f(bb[ccol]);
#pragma unroll
        for (int i = 0; i < 4; ++i) {
            float v = acc[i] + bv;
            v = v > 0.f ? v : 0.f;
            size_t oi = (size_t)(m0 + quad * 4 + i) * NOUT + ccol;
            if (fp32out) ((float*)hout)[oi] = v;
            else ((unsigned short*)hout)[oi] = f2bfbits(v);
        }
    }
}

// ---------------- orchestration ----------------
extern "C" void kernel_launch(void* const* d_in, const int* in_sizes, int n_in,
                              void* d_out, int out_size, void* d_ws, size_t ws_size,
                              hipStream_t stream) {
    const void* x  = d_in[0];
    const int* e[3] = { (const int*)d_in[1], (const int*)d_in[2], (const int*)d_in[3] };
    const void* Wl[3] = { d_in[4], d_in[7], d_in[10] };
    const void* bl[3] = { d_in[5], d_in[8], d_in[11] };
    const void* Wr[3] = { d_in[6], d_in[9], d_in[12] };

    char* ws = (char*)d_ws;
    int* flags  = (int*)ws;                                   // @0, 2 ints
    unsigned short* wt = (unsigned short*)(ws + 4096);
    unsigned short* WlT0 = wt;                                // 128x256 -> 32768
    unsigned short* WrT0 = wt + 32768;
    unsigned short* WlT1 = wt + 65536;                        // 256x256 -> 65536
    unsigned short* WrT1 = wt + 131072;
    unsigned short* WlT2 = wt + 196608;                       // 256x128 -> 32768
    unsigned short* WrT2 = wt + 229376;
    unsigned short* bb0  = wt + 262144;
    unsigned short* bb1  = wt + 262400;
    unsigned short* bb2  = wt + 262656;
    int* cnt     = (int*)(ws + 1000000);                      // 200 KB
    int* rowptr  = (int*)(ws + 1200000);                      // 200 KB
    int* cursor  = (int*)(ws + 1400320);                      // 200 KB
    int* csr_src = (int*)(ws + 1600512);                      // 3.2 MB
    unsigned short* hA = (unsigned short*)(ws + 4800512);     // 25.6 MB
    unsigned short* hB = (unsigned short*)(ws + 30400512);    // 25.6 MB
    // total ~56.0 MB

    detect<<<1, 256, 0, stream>>>((const unsigned short*)x, e[0], flags);

    prep_w<<<128, 256, 0, stream>>>(Wl[0], WlT0, 128, 256, flags);
    prep_w<<<128, 256, 0, stream>>>(Wr[0], WrT0, 128, 256, flags);
    prep_w<<<256, 256, 0, stream>>>(Wl[1], WlT1, 256, 256, flags);
    prep_w<<<256, 256, 0, stream>>>(Wr[1], WrT1, 256, 256, flags);
    prep_w<<<128, 256, 0, stream>>>(Wl[2], WlT2, 256, 128, flags);
    prep_w<<<128, 256, 0, stream>>>(Wr[2], WrT2, 256, 128, flags);
    prep_vec<<<1, 256, 0, stream>>>(bl[0], bb0, 256, flags);
    prep_vec<<<1, 256, 0, stream>>>(bl[1], bb1, 256, flags);
    prep_vec<<<1, 256, 0, stream>>>(bl[2], bb2, 128, flags);

    const int ZG = (N_NODES + 255) / 256;       // 196
    const int EG = N_EDGES / 256;               // 3125
    const int MG = N_NODES / 16;                // 3125

    // layer 0: x[.,128] -> hA[.,256]
    zero_two<<<ZG, 256, 0, stream>>>(cnt, cursor, N_NODES);
    edge_count<<<EG, 256, 0, stream>>>(e[0], cnt, flags);
    scan_rowptr<<<1, 256, 0, stream>>>(cnt, rowptr);
    edge_fill<<<EG, 256, 0, stream>>>(e[0], rowptr, cursor, csr_src, flags);
    sage_fused<128, 256, false><<<MG, 256, 0, stream>>>(
        x, rowptr, cnt, csr_src, WlT0, WrT0, bb0, hA, flags, 1);

    // layer 1: hA[.,256] -> hB[.,256]
    zero_two<<<ZG, 256, 0, stream>>>(cnt, cursor, N_NODES);
    edge_count<<<EG, 256, 0, stream>>>(e[1], cnt, flags);
    scan_rowptr<<<1, 256, 0, stream>>>(cnt, rowptr);
    edge_fill<<<EG, 256, 0, stream>>>(e[1], rowptr, cursor, csr_src, flags);
    sage_fused<256, 256, false><<<MG, 256, 0, stream>>>(
        hA, rowptr, cnt, csr_src, WlT1, WrT1, bb1, hB, flags, 0);

    // layer 2: hB[.,256] -> d_out[.,128]
    zero_two<<<ZG, 256, 0, stream>>>(cnt, cursor, N_NODES);
    edge_count<<<EG, 256, 0, stream>>>(e[2], cnt, flags);
    scan_rowptr<<<1, 256, 0, stream>>>(cnt, rowptr);
    edge_fill<<<EG, 256, 0, stream>>>(e[2], rowptr, cursor, csr_src, flags);
    sage_fused<256, 128, true><<<MG, 256, 0, stream>>>(
        hB, rowptr, cnt, csr_src, WlT2, WrT2, bb2, d_out, flags, 0);
}

// Round 4
// 808.606 us; speedup vs baseline: 1.7462x; 1.7462x over previous
//
#include <hip/hip_runtime.h>
#include <hip/hip_bf16.h>
#include <stdint.h>

#define N_NODES 50000
#define N_EDGES 800000
#define NBLK 196                 // ceil(50000/256)

typedef __attribute__((ext_vector_type(8))) short short8;
typedef __attribute__((ext_vector_type(4))) float floatx4;

__device__ __forceinline__ float bfbits2f(unsigned int u16) {
    union { unsigned int i; float f; } c; c.i = u16 << 16; return c.f;
}
__device__ __forceinline__ unsigned short f2bfbits(float f) {
    union { float f; unsigned int i; } c; c.f = f;
    unsigned int r = c.i + 0x7fffu + ((c.i >> 16) & 1u);   // RNE
    return (unsigned short)(r >> 16);
}

// ---------------- dtype detection (1 block) — verified r2, DO NOT TOUCH ----------------
__global__ __launch_bounds__(256) void detect(
    const unsigned short* __restrict__ x16, const int* __restrict__ e,
    int* __restrict__ flags)
{
    __shared__ int s_cnt[2];
    const int t = threadIdx.x;
    if (t < 2) s_cnt[t] = 0;
    __syncthreads();
    unsigned short v = x16[2 * t];
    int ex = (v >> 7) & 0xff;
    if (v == 0 || (ex >= 96 && ex <= 150)) atomicAdd(&s_cnt[0], 1);
    if (e[2 * t + 1] != 0) atomicAdd(&s_cnt[1], 1);
    __syncthreads();
    if (t == 0) {
        flags[0] = (s_cnt[0] < 200) ? 1 : 0;
        flags[1] = (s_cnt[1] < 128) ? 1 : 0;
    }
}

// ---------------- merged weight/bias prep ----------------
__global__ __launch_bounds__(256) void prep_all(
    const void* __restrict__ Wl0, const void* __restrict__ Wr0,
    const void* __restrict__ Wl1, const void* __restrict__ Wr1,
    const void* __restrict__ Wl2, const void* __restrict__ Wr2,
    const void* __restrict__ b0, const void* __restrict__ b1, const void* __restrict__ b2,
    unsigned short* __restrict__ wt, const int* __restrict__ flags)
{
    const int bid = blockIdx.x, t = threadIdx.x;
    const int f = flags[0];
    if (bid >= 1024) {                       // biases
        const void* bs = bid == 1024 ? b0 : (bid == 1025 ? b1 : b2);
        unsigned short* bd = wt + 262144 + (bid - 1024) * 256;
        int n = (bid == 1026) ? 128 : 256;
        if (t < n) bd[t] = f ? f2bfbits(((const float*)bs)[t]) : ((const unsigned short*)bs)[t];
        return;
    }
    const void* W; unsigned short* WT; int K, N, off;
    if (bid < 128)      { W = Wl0; WT = wt;          K = 128; N = 256; off = bid; }
    else if (bid < 256) { W = Wr0; WT = wt + 32768;  K = 128; N = 256; off = bid - 128; }
    else if (bid < 512) { W = Wl1; WT = wt + 65536;  K = 256; N = 256; off = bid - 256; }
    else if (bid < 768) { W = Wr1; WT = wt + 131072; K = 256; N = 256; off = bid - 512; }
    else if (bid < 896) { W = Wl2; WT = wt + 196608; K = 256; N = 128; off = bid - 768; }
    else                { W = Wr2; WT = wt + 229376; K = 256; N = 128; off = bid - 896; }
    int idx = off * 256 + t;
    int k = idx / N, n = idx - k * N;
    unsigned short v = f ? f2bfbits(((const float*)W)[idx]) : ((const unsigned short*)W)[idx];
    WT[n * K + k] = v;
}

// ---------------- CSR build ----------------
__global__ __launch_bounds__(256) void zero_cnt(int* __restrict__ cnt) {
    int i = blockIdx.x * 256 + threadIdx.x;
    if (i < N_NODES) cnt[i] = 0;
}

__global__ __launch_bounds__(256) void edge_count(
    const int* __restrict__ e, int* __restrict__ cnt, const int* __restrict__ flags)
{
    int i = blockIdx.x * 256 + threadIdx.x;
    int dst = flags[1] ? e[2 * (N_EDGES + i)] : e[N_EDGES + i];
    atomicAdd(&cnt[dst], 1);
}

// local (per-256-tile) exclusive scan; per-tile totals to part[]
__global__ __launch_bounds__(256) void scan_k1(
    const int* __restrict__ cnt, int* __restrict__ rp, int* __restrict__ part)
{
    __shared__ int sa[256], sb[256];
    const int b = blockIdx.x, t = threadIdx.x, idx = b * 256 + t;
    int v = (idx < N_NODES) ? cnt[idx] : 0;
    sa[t] = v;
    __syncthreads();
    bool par = true;
#pragma unroll
    for (int off = 1; off < 256; off <<= 1) {
        if (par) { int x = sa[t] + (t >= off ? sa[t - off] : 0); sb[t] = x; }
        else     { int x = sb[t] + (t >= off ? sb[t - off] : 0); sa[t] = x; }
        par = !par;
        __syncthreads();
    }
    if (idx < N_NODES) rp[idx] = sa[t] - v;          // local exclusive
    if (t == 255) part[b] = sa[255];
}

// exclusive-scan the 196 tile totals (1 block)
__global__ __launch_bounds__(256) void scan_k2(int* __restrict__ part) {
    __shared__ int sa[256], sb[256];
    const int t = threadIdx.x;
    int v = (t < NBLK) ? part[t] : 0;
    sa[t] = v;
    __syncthreads();
    bool par = true;
#pragma unroll
    for (int off = 1; off < 256; off <<= 1) {
        if (par) { int x = sa[t] + (t >= off ? sa[t - off] : 0); sb[t] = x; }
        else     { int x = sb[t] + (t >= off ? sb[t - off] : 0); sa[t] = x; }
        par = !par;
        __syncthreads();
    }
    if (t < NBLK) part[t] = sa[t] - v;               // exclusive
}

// add tile offsets, finalize rowptr, init fill cursor
__global__ __launch_bounds__(256) void scan_k3(
    int* __restrict__ rp, const int* __restrict__ part, int* __restrict__ cur)
{
    const int b = blockIdx.x, idx = b * 256 + threadIdx.x;
    int o = part[b];
    if (idx < N_NODES) {
        int v = rp[idx] + o;
        rp[idx] = v;
        cur[idx] = v;
    } else if (idx == N_NODES) {
        rp[idx] = N_EDGES;
    }
}

__global__ __launch_bounds__(256) void edge_fill(
    const int* __restrict__ e, int* __restrict__ cur, int* __restrict__ csr,
    const int* __restrict__ flags)
{
    int i = blockIdx.x * 256 + threadIdx.x;
    int f = flags[1];
    int src = f ? e[2 * i] : e[i];
    int dst = f ? e[2 * (N_EDGES + i)] : e[N_EDGES + i];
    csr[atomicAdd(&cur[dst], 1)] = src;
}

// ---------------- fused layer: CSR mean-aggregate + dual GEMM + bias + relu ----------------
// block = 256 threads, 16-node m-tile.
// Phase 1: (row,chunk)-parallel gather — thread owns (node rr, 16B chunk cc),
// loops over rr's edges accumulating in registers (no atomics, loads independent).
template<int K, int NOUT, bool FINAL>
__global__ __launch_bounds__(256) void sage_fused(
    const void* __restrict__ hin,
    const int* __restrict__ rowptr,
    const int* __restrict__ csr_src,
    const unsigned short* __restrict__ WlT,
    const unsigned short* __restrict__ WrT,
    const unsigned short* __restrict__ bb,
    void* __restrict__ hout,
    const int* __restrict__ flags,
    int layer0)
{
    constexpr int CH = K / 8;                 // 16B chunks per row (bf16)
    __shared__ unsigned short A0s[16][K + 8];
    __shared__ int srp[17];
    const int tid = threadIdx.x;
    const int m0 = blockIdx.x * 16;
    if (tid < 17) srp[tid] = rowptr[m0 + tid];
    __syncthreads();
    const int fp32in = layer0 ? flags[0] : 0;

    // ---- phase 1 ----
    for (int it = tid; it < 16 * CH; it += 256) {
        const int rr = it / CH;
        const int cc = it & (CH - 1);
        const int beg = srp[rr];
        const int deg = srp[rr + 1] - beg;
        float a[8], g[8];
#pragma unroll
        for (int v = 0; v < 8; ++v) { a[v] = 0.f; g[v] = 0.f; }
        if (!fp32in) {
            const unsigned short* col = (const unsigned short*)hin + cc * 8;
            int j = 0;
            for (; j + 1 < deg; j += 2) {
                int s0 = csr_src[beg + j];
                int s1 = csr_src[beg + j + 1];
                uint4 v0 = *(const uint4*)(col + (size_t)s0 * K);
                uint4 v1 = *(const uint4*)(col + (size_t)s1 * K);
                a[0] += bfbits2f(v0.x & 0xffffu); a[1] += bfbits2f(v0.x >> 16);
                a[2] += bfbits2f(v0.y & 0xffffu); a[3] += bfbits2f(v0.y >> 16);
                a[4] += bfbits2f(v0.z & 0xffffu); a[5] += bfbits2f(v0.z >> 16);
                a[6] += bfbits2f(v0.w & 0xffffu); a[7] += bfbits2f(v0.w >> 16);
                g[0] += bfbits2f(v1.x & 0xffffu); g[1] += bfbits2f(v1.x >> 16);
                g[2] += bfbits2f(v1.y & 0xffffu); g[3] += bfbits2f(v1.y >> 16);
                g[4] += bfbits2f(v1.z & 0xffffu); g[5] += bfbits2f(v1.z >> 16);
                g[6] += bfbits2f(v1.w & 0xffffu); g[7] += bfbits2f(v1.w >> 16);
            }
            if (j < deg) {
                int s0 = csr_src[beg + j];
                uint4 v0 = *(const uint4*)(col + (size_t)s0 * K);
                a[0] += bfbits2f(v0.x & 0xffffu); a[1] += bfbits2f(v0.x >> 16);
                a[2] += bfbits2f(v0.y & 0xffffu); a[3] += bfbits2f(v0.y >> 16);
                a[4] += bfbits2f(v0.z & 0xffffu); a[5] += bfbits2f(v0.z >> 16);
                a[6] += bfbits2f(v0.w & 0xffffu); a[7] += bfbits2f(v0.w >> 16);
            }
        } else {
            // layer 0 fp32 features (K=128): chunk = 8 floats = two float4 loads.
            // a[0..7] accumulates edge j, g[0..7] accumulates edge j+1 (same
            // feature indices — r3 BUG was folding features 4..7 into 0..3).
            const float* col = (const float*)hin + cc * 8;
            int j = 0;
            for (; j + 1 < deg; j += 2) {
                int s0 = csr_src[beg + j];
                int s1 = csr_src[beg + j + 1];
                float4 v0 = *(const float4*)(col + (size_t)s0 * K);
                float4 v1 = *(const float4*)(col + (size_t)s0 * K + 4);
                float4 w0 = *(const float4*)(col + (size_t)s1 * K);
                float4 w1 = *(const float4*)(col + (size_t)s1 * K + 4);
                a[0] += v0.x; a[1] += v0.y; a[2] += v0.z; a[3] += v0.w;
                a[4] += v1.x; a[5] += v1.y; a[6] += v1.z; a[7] += v1.w;
                g[0] += w0.x; g[1] += w0.y; g[2] += w0.z; g[3] += w0.w;
                g[4] += w1.x; g[5] += w1.y; g[6] += w1.z; g[7] += w1.w;
            }
            if (j < deg) {
                int s0 = csr_src[beg + j];
                float4 v0 = *(const float4*)(col + (size_t)s0 * K);
                float4 v1 = *(const float4*)(col + (size_t)s0 * K + 4);
                a[0] += v0.x; a[1] += v0.y; a[2] += v0.z; a[3] += v0.w;
                a[4] += v1.x; a[5] += v1.y; a[6] += v1.z; a[7] += v1.w;
            }
        }
        const float inv = 1.0f / fmaxf((float)deg, 1.0f);
        short8 t8;
#pragma unroll
        for (int v = 0; v < 8; ++v) t8[v] = (short)f2bfbits((a[v] + g[v]) * inv);
        *(short8*)&A0s[rr][cc * 8] = t8;
    }
    __syncthreads();

    // ---- phase 2: MFMA dual GEMM ----
    const int lane = tid & 63;
    const int wave = tid >> 6;
    const int r = lane & 15;
    const int quad = lane >> 4;
    short8 a0f[K / 32], a1f[K / 32];
#pragma unroll
    for (int k0 = 0; k0 < K / 32; ++k0)
        a0f[k0] = *(const short8*)&A0s[r][k0 * 32 + quad * 8];
    if (!fp32in) {
        const unsigned short* hb = (const unsigned short*)hin + (size_t)(m0 + r) * K + quad * 8;
#pragma unroll
        for (int k0 = 0; k0 < K / 32; ++k0)
            a1f[k0] = *(const short8*)(hb + k0 * 32);
    } else {
        const float* hf = (const float*)hin + (size_t)(m0 + r) * K + quad * 8;
#pragma unroll
        for (int k0 = 0; k0 < K / 32; ++k0) {
            floatx4 a = *(const floatx4*)(hf + k0 * 32);
            floatx4 b = *(const floatx4*)(hf + k0 * 32 + 4);
            short8 t;
            t[0] = (short)f2bfbits(a.x); t[1] = (short)f2bfbits(a.y);
            t[2] = (short)f2bfbits(a.z); t[3] = (short)f2bfbits(a.w);
            t[4] = (short)f2bfbits(b.x); t[5] = (short)f2bfbits(b.y);
            t[6] = (short)f2bfbits(b.z); t[7] = (short)f2bfbits(b.w);
            a1f[k0] = t;
        }
    }
    const int fp32out = FINAL ? flags[0] : 0;

    for (int nt = wave; nt < NOUT / 16; nt += 4) {
        const int n0 = nt * 16;
        floatx4 acc = {0.f, 0.f, 0.f, 0.f};
        const unsigned short* b0 = WlT + (size_t)(n0 + r) * K + quad * 8;
        const unsigned short* b1 = WrT + (size_t)(n0 + r) * K + quad * 8;
#pragma unroll
        for (int k0 = 0; k0 < K / 32; ++k0)
            acc = __builtin_amdgcn_mfma_f32_16x16x32_bf16(a0f[k0], *(const short8*)(b0 + k0 * 32), acc, 0, 0, 0);
#pragma unroll
        for (int k0 = 0; k0 < K / 32; ++k0)
            acc = __builtin_amdgcn_mfma_f32_16x16x32_bf16(a1f[k0], *(const short8*)(b1 + k0 * 32), acc, 0, 0, 0);

        // C/D layout: col = lane&15, row = quad*4 + reg  [HW-verified]
        const int ccol = n0 + r;
        float bv = bfbits2f(bb[ccol]);
#pragma unroll
        for (int i = 0; i < 4; ++i) {
            float v = acc[i] + bv;
            v = v > 0.f ? v : 0.f;
            size_t oi = (size_t)(m0 + quad * 4 + i) * NOUT + ccol;
            if (fp32out) ((float*)hout)[oi] = v;
            else ((unsigned short*)hout)[oi] = f2bfbits(v);
        }
    }
}

// ---------------- orchestration ----------------
extern "C" void kernel_launch(void* const* d_in, const int* in_sizes, int n_in,
                              void* d_out, int out_size, void* d_ws, size_t ws_size,
                              hipStream_t stream) {
    const void* x  = d_in[0];
    const int* e[3] = { (const int*)d_in[1], (const int*)d_in[2], (const int*)d_in[3] };

    char* ws = (char*)d_ws;
    int* flags = (int*)ws;                                    // @0
    unsigned short* wt = (unsigned short*)(ws + 1024);        // 525568 B
    unsigned short* bb0 = wt + 262144;
    unsigned short* bb1 = wt + 262400;
    unsigned short* bb2 = wt + 262656;
    int* cnt  = (int*)(ws + 526592);                          // 200000 B
    int* rp   = (int*)(ws + 726592);                          // 200004 B
    int* cur  = (int*)(ws + 926596);                          // 200000 B
    int* part = (int*)(ws + 1126596);                         // 784 B
    int* csr  = (int*)(ws + 1127392);                         // 3.2 MB
    unsigned short* hA = (unsigned short*)(ws + 4327392);     // 25.6 MB
    unsigned short* hB = (unsigned short*)(ws + 29927392);    // 25.6 MB
    // total 55.53 MB (within the r2-proven 56 MB envelope)

    detect<<<1, 256, 0, stream>>>((const unsigned short*)x, e[0], flags);
    prep_all<<<1027, 256, 0, stream>>>(d_in[4], d_in[6], d_in[7], d_in[9],
                                       d_in[10], d_in[12], d_in[5], d_in[8], d_in[11],
                                       wt, flags);

    const int EG = N_EDGES / 256;     // 3125
    const int MG = N_NODES / 16;      // 3125

    // ---- layer 0: x[.,128] -> hA[.,256] ----
    zero_cnt<<<NBLK, 256, 0, stream>>>(cnt);
    edge_count<<<EG, 256, 0, stream>>>(e[0], cnt, flags);
    scan_k1<<<NBLK, 256, 0, stream>>>(cnt, rp, part);
    scan_k2<<<1, 256, 0, stream>>>(part);
    scan_k3<<<NBLK, 256, 0, stream>>>(rp, part, cur);
    edge_fill<<<EG, 256, 0, stream>>>(e[0], cur, csr, flags);
    sage_fused<128, 256, false><<<MG, 256, 0, stream>>>(
        x, rp, csr, wt, wt + 32768, bb0, hA, flags, 1);

    // ---- layer 1: hA[.,256] -> hB[.,256] ----
    zero_cnt<<<NBLK, 256, 0, stream>>>(cnt);
    edge_count<<<EG, 256, 0, stream>>>(e[1], cnt, flags);
    scan_k1<<<NBLK, 256, 0, stream>>>(cnt, rp, part);
    scan_k2<<<1, 256, 0, stream>>>(part);
    scan_k3<<<NBLK, 256, 0, stream>>>(rp, part, cur);
    edge_fill<<<EG, 256, 0, stream>>>(e[1], cur, csr, flags);
    sage_fused<256, 256, false><<<MG, 256, 0, stream>>>(
        hA, rp, csr, wt + 65536, wt + 131072, bb1, hB, flags, 0);

    // ---- layer 2: hB[.,256] -> d_out[.,128] ----
    zero_cnt<<<NBLK, 256, 0, stream>>>(cnt);
    edge_count<<<EG, 256, 0, stream>>>(e[2], cnt, flags);
    scan_k1<<<NBLK, 256, 0, stream>>>(cnt, rp, part);
    scan_k2<<<1, 256, 0, stream>>>(part);
    scan_k3<<<NBLK, 256, 0, stream>>>(rp, part, cur);
    edge_fill<<<EG, 256, 0, stream>>>(e[2], cur, csr, flags);
    sage_fused<256, 128, true><<<MG, 256, 0, stream>>>(
        hB, rp, csr, wt + 196608, wt + 229376, bb2, d_out, flags, 0);
}

// Round 5
// 748.220 us; speedup vs baseline: 1.8872x; 1.0807x over previous
//
#include <hip/hip_runtime.h>
#include <hip/hip_bf16.h>
#include <stdint.h>

#define N_NODES 50000
#define N_EDGES 800000
#define NBLK 196                 // ceil(50000/256)

typedef __attribute__((ext_vector_type(8))) short short8;
typedef __attribute__((ext_vector_type(4))) float floatx4;

__device__ __forceinline__ float bfbits2f(unsigned int u16) {
    union { unsigned int i; float f; } c; c.i = u16 << 16; return c.f;
}
__device__ __forceinline__ unsigned short f2bfbits(float f) {
    union { float f; unsigned int i; } c; c.f = f;
    unsigned int r = c.i + 0x7fffu + ((c.i >> 16) & 1u);   // RNE
    return (unsigned short)(r >> 16);
}
__device__ __forceinline__ void acc8(float* a, uint4 v) {
    a[0] += bfbits2f(v.x & 0xffffu); a[1] += bfbits2f(v.x >> 16);
    a[2] += bfbits2f(v.y & 0xffffu); a[3] += bfbits2f(v.y >> 16);
    a[4] += bfbits2f(v.z & 0xffffu); a[5] += bfbits2f(v.z >> 16);
    a[6] += bfbits2f(v.w & 0xffffu); a[7] += bfbits2f(v.w >> 16);
}

// ---------------- dtype detection (1 block) — verified r2, DO NOT TOUCH ----------------
__global__ __launch_bounds__(256) void detect(
    const unsigned short* __restrict__ x16, const int* __restrict__ e,
    int* __restrict__ flags)
{
    __shared__ int s_cnt[2];
    const int t = threadIdx.x;
    if (t < 2) s_cnt[t] = 0;
    __syncthreads();
    unsigned short v = x16[2 * t];
    int ex = (v >> 7) & 0xff;
    if (v == 0 || (ex >= 96 && ex <= 150)) atomicAdd(&s_cnt[0], 1);
    if (e[2 * t + 1] != 0) atomicAdd(&s_cnt[1], 1);
    __syncthreads();
    if (t == 0) {
        flags[0] = (s_cnt[0] < 200) ? 1 : 0;
        flags[1] = (s_cnt[1] < 128) ? 1 : 0;
    }
}

// ---------------- merged weight/bias prep (verified r4) ----------------
__global__ __launch_bounds__(256) void prep_all(
    const void* __restrict__ Wl0, const void* __restrict__ Wr0,
    const void* __restrict__ Wl1, const void* __restrict__ Wr1,
    const void* __restrict__ Wl2, const void* __restrict__ Wr2,
    const void* __restrict__ b0, const void* __restrict__ b1, const void* __restrict__ b2,
    unsigned short* __restrict__ wt, const int* __restrict__ flags)
{
    const int bid = blockIdx.x, t = threadIdx.x;
    const int f = flags[0];
    if (bid >= 1024) {                       // biases
        const void* bs = bid == 1024 ? b0 : (bid == 1025 ? b1 : b2);
        unsigned short* bd = wt + 262144 + (bid - 1024) * 256;
        int n = (bid == 1026) ? 128 : 256;
        if (t < n) bd[t] = f ? f2bfbits(((const float*)bs)[t]) : ((const unsigned short*)bs)[t];
        return;
    }
    const void* W; unsigned short* WT; int K, N, off;
    if (bid < 128)      { W = Wl0; WT = wt;          K = 128; N = 256; off = bid; }
    else if (bid < 256) { W = Wr0; WT = wt + 32768;  K = 128; N = 256; off = bid - 128; }
    else if (bid < 512) { W = Wl1; WT = wt + 65536;  K = 256; N = 256; off = bid - 256; }
    else if (bid < 768) { W = Wr1; WT = wt + 131072; K = 256; N = 256; off = bid - 512; }
    else if (bid < 896) { W = Wl2; WT = wt + 196608; K = 256; N = 128; off = bid - 768; }
    else                { W = Wr2; WT = wt + 229376; K = 256; N = 128; off = bid - 896; }
    int idx = off * 256 + t;
    int k = idx / N, n = idx - k * N;
    unsigned short v = f ? f2bfbits(((const float*)W)[idx]) : ((const unsigned short*)W)[idx];
    WT[n * K + k] = v;
}

// ---------------- x -> bf16 (halves layer-0 gather volume) ----------------
__global__ __launch_bounds__(256) void cvt_x(
    const void* __restrict__ x, unsigned short* __restrict__ xb,
    const int* __restrict__ flags)
{
    int i = blockIdx.x * 256 + threadIdx.x;      // 4 elements per thread
    if (flags[0]) {
        float4 v = ((const float4*)x)[i];
        uint2 o;
        o.x = (unsigned int)f2bfbits(v.x) | ((unsigned int)f2bfbits(v.y) << 16);
        o.y = (unsigned int)f2bfbits(v.z) | ((unsigned int)f2bfbits(v.w) << 16);
        ((uint2*)xb)[i] = o;
    } else {
        ((uint2*)xb)[i] = ((const uint2*)x)[i];
    }
}

// ---------------- CSR build (verified r4, unchanged) ----------------
__global__ __launch_bounds__(256) void zero_cnt(int* __restrict__ cnt) {
    int i = blockIdx.x * 256 + threadIdx.x;
    if (i < N_NODES) cnt[i] = 0;
}

__global__ __launch_bounds__(256) void edge_count(
    const int* __restrict__ e, int* __restrict__ cnt, const int* __restrict__ flags)
{
    int i = blockIdx.x * 256 + threadIdx.x;
    int dst = flags[1] ? e[2 * (N_EDGES + i)] : e[N_EDGES + i];
    atomicAdd(&cnt[dst], 1);
}

__global__ __launch_bounds__(256) void scan_k1(
    const int* __restrict__ cnt, int* __restrict__ rp, int* __restrict__ part)
{
    __shared__ int sa[256], sb[256];
    const int b = blockIdx.x, t = threadIdx.x, idx = b * 256 + t;
    int v = (idx < N_NODES) ? cnt[idx] : 0;
    sa[t] = v;
    __syncthreads();
    bool par = true;
#pragma unroll
    for (int off = 1; off < 256; off <<= 1) {
        if (par) { int x = sa[t] + (t >= off ? sa[t - off] : 0); sb[t] = x; }
        else     { int x = sb[t] + (t >= off ? sb[t - off] : 0); sa[t] = x; }
        par = !par;
        __syncthreads();
    }
    if (idx < N_NODES) rp[idx] = sa[t] - v;
    if (t == 255) part[b] = sa[255];
}

__global__ __launch_bounds__(256) void scan_k2(int* __restrict__ part) {
    __shared__ int sa[256], sb[256];
    const int t = threadIdx.x;
    int v = (t < NBLK) ? part[t] : 0;
    sa[t] = v;
    __syncthreads();
    bool par = true;
#pragma unroll
    for (int off = 1; off < 256; off <<= 1) {
        if (par) { int x = sa[t] + (t >= off ? sa[t - off] : 0); sb[t] = x; }
        else     { int x = sb[t] + (t >= off ? sb[t - off] : 0); sa[t] = x; }
        par = !par;
        __syncthreads();
    }
    if (t < NBLK) part[t] = sa[t] - v;
}

__global__ __launch_bounds__(256) void scan_k3(
    int* __restrict__ rp, const int* __restrict__ part, int* __restrict__ cur)
{
    const int b = blockIdx.x, idx = b * 256 + threadIdx.x;
    int o = part[b];
    if (idx < N_NODES) {
        int v = rp[idx] + o;
        rp[idx] = v;
        cur[idx] = v;
    } else if (idx == N_NODES) {
        rp[idx] = N_EDGES;
    }
}

__global__ __launch_bounds__(256) void edge_fill(
    const int* __restrict__ e, int* __restrict__ cur, int* __restrict__ csr,
    const int* __restrict__ flags)
{
    int i = blockIdx.x * 256 + threadIdx.x;
    int f = flags[1];
    int src = f ? e[2 * i] : e[i];
    int dst = f ? e[2 * (N_EDGES + i)] : e[N_EDGES + i];
    csr[atomicAdd(&cur[dst], 1)] = src;
}

// ---------------- fused layer (L0/L1): CSR mean-agg + dual GEMM + bias + relu ----------------
// All-bf16. Phase 1: LDS-staged edge indices + unroll-4 gather (4 loads in flight).
template<int K>
__global__ __launch_bounds__(256) void sage_fused(
    const unsigned short* __restrict__ hin,   // [N,K] bf16
    const int* __restrict__ rowptr,
    const int* __restrict__ csr_src,
    const unsigned short* __restrict__ WlT,   // [256,K]
    const unsigned short* __restrict__ WrT,   // [256,K]
    const unsigned short* __restrict__ bb,    // [256]
    unsigned short* __restrict__ hout)        // [N,256]
{
    constexpr int CH = K / 8;                 // 16B chunks per row
    constexpr int CAP = 3072;
    __shared__ unsigned short A0s[16][K + 8];
    __shared__ int sidx[CAP];
    __shared__ int srp[17];
    const int tid = threadIdx.x;
    const int m0 = blockIdx.x * 16;
    if (tid < 17) srp[tid] = rowptr[m0 + tid];
    __syncthreads();
    const int base = srp[0];
    const int total = srp[16] - base;
    const bool staged = total <= CAP;         // uniform across block
    if (staged) {
        for (int i = tid; i < total; i += 256) sidx[i] = csr_src[base + i];
    }
    __syncthreads();

    // ---- phase 1: gather + mean ----
    for (int it = tid; it < 16 * CH; it += 256) {
        const int rr = it / CH;
        const int cc = it & (CH - 1);
        const int beg = srp[rr];
        const int deg = srp[rr + 1] - beg;
        const int begl = beg - base;
        float a[8], g[8];
#pragma unroll
        for (int v = 0; v < 8; ++v) { a[v] = 0.f; g[v] = 0.f; }
        const unsigned short* col = hin + cc * 8;
        auto run = [&](auto IDX) {
            int j = 0;
            for (; j + 3 < deg; j += 4) {
                int s0 = IDX(j), s1 = IDX(j + 1), s2 = IDX(j + 2), s3 = IDX(j + 3);
                uint4 v0 = *(const uint4*)(col + (size_t)s0 * K);
                uint4 v1 = *(const uint4*)(col + (size_t)s1 * K);
                uint4 v2 = *(const uint4*)(col + (size_t)s2 * K);
                uint4 v3 = *(const uint4*)(col + (size_t)s3 * K);
                acc8(a, v0); acc8(g, v1); acc8(a, v2); acc8(g, v3);
            }
            for (; j < deg; ++j) {
                uint4 v0 = *(const uint4*)(col + (size_t)IDX(j) * K);
                acc8(a, v0);
            }
        };
        if (staged) run([&](int j) { return sidx[begl + j]; });
        else        run([&](int j) { return csr_src[beg + j]; });
        const float inv = 1.0f / fmaxf((float)deg, 1.0f);
        short8 t8;
#pragma unroll
        for (int v = 0; v < 8; ++v) t8[v] = (short)f2bfbits((a[v] + g[v]) * inv);
        *(short8*)&A0s[rr][cc * 8] = t8;
    }
    __syncthreads();

    // ---- phase 2: MFMA dual GEMM + bias + relu (verified r4) ----
    const int lane = tid & 63;
    const int wave = tid >> 6;
    const int r = lane & 15;
    const int quad = lane >> 4;
    short8 a0f[K / 32], a1f[K / 32];
#pragma unroll
    for (int k0 = 0; k0 < K / 32; ++k0)
        a0f[k0] = *(const short8*)&A0s[r][k0 * 32 + quad * 8];
    const unsigned short* hb = hin + (size_t)(m0 + r) * K + quad * 8;
#pragma unroll
    for (int k0 = 0; k0 < K / 32; ++k0)
        a1f[k0] = *(const short8*)(hb + k0 * 32);

    for (int nt = wave; nt < 16; nt += 4) {
        const int n0 = nt * 16;
        floatx4 acc = {0.f, 0.f, 0.f, 0.f};
        const unsigned short* b0 = WlT + (size_t)(n0 + r) * K + quad * 8;
        const unsigned short* b1 = WrT + (size_t)(n0 + r) * K + quad * 8;
#pragma unroll
        for (int k0 = 0; k0 < K / 32; ++k0)
            acc = __builtin_amdgcn_mfma_f32_16x16x32_bf16(a0f[k0], *(const short8*)(b0 + k0 * 32), acc, 0, 0, 0);
#pragma unroll
        for (int k0 = 0; k0 < K / 32; ++k0)
            acc = __builtin_amdgcn_mfma_f32_16x16x32_bf16(a1f[k0], *(const short8*)(b1 + k0 * 32), acc, 0, 0, 0);

        // C/D layout: col = lane&15, row = quad*4 + reg  [HW-verified]
        const int ccol = n0 + r;
        float bv = bfbits2f(bb[ccol]);
#pragma unroll
        for (int i = 0; i < 4; ++i) {
            float v = acc[i] + bv;
            v = v > 0.f ? v : 0.f;
            hout[(size_t)(m0 + quad * 4 + i) * 256 + ccol] = f2bfbits(v);
        }
    }
}

// ---------------- L2 GEMM pair: hl2 = hB@Wl2, hr2 = hB@Wr2 (no bias/relu) ----------------
__global__ __launch_bounds__(256) void gemm_pair(
    const unsigned short* __restrict__ A,     // hB [N,256]
    const unsigned short* __restrict__ WT,    // [256,256] = concat(WlT2, WrT2)
    unsigned short* __restrict__ out0,        // hl2 [N,128]
    unsigned short* __restrict__ out1)        // hr2 [N,128]
{
    const int tid = threadIdx.x, lane = tid & 63, wave = tid >> 6;
    const int m0 = blockIdx.x * 16;
    const int r = lane & 15, quad = lane >> 4;
    short8 af[8];
    const unsigned short* ab = A + (size_t)(m0 + r) * 256 + quad * 8;
#pragma unroll
    for (int k0 = 0; k0 < 8; ++k0) af[k0] = *(const short8*)(ab + k0 * 32);

    for (int nt = wave; nt < 16; nt += 4) {
        const int n0 = nt * 16;
        floatx4 acc = {0.f, 0.f, 0.f, 0.f};
        const unsigned short* b0 = WT + (size_t)(n0 + r) * 256 + quad * 8;
#pragma unroll
        for (int k0 = 0; k0 < 8; ++k0)
            acc = __builtin_amdgcn_mfma_f32_16x16x32_bf16(af[k0], *(const short8*)(b0 + k0 * 32), acc, 0, 0, 0);
        const int ccol = n0 + r;
#pragma unroll
        for (int i = 0; i < 4; ++i) {
            const size_t row = m0 + quad * 4 + i;
            unsigned short v = f2bfbits(acc[i]);
            if (ccol < 128) out0[row * 128 + ccol] = v;
            else            out1[row * 128 + ccol - 128] = v;
        }
    }
}

// ---------------- L2 aggregate + epilogue: out = relu(mean(hl2) + b2 + hr2) ----------------
__global__ __launch_bounds__(256) void agg2(
    const unsigned short* __restrict__ hl2,   // [N,128]
    const unsigned short* __restrict__ hr2,   // [N,128]
    const int* __restrict__ rowptr,
    const int* __restrict__ csr_src,
    const unsigned short* __restrict__ bb,    // [128]
    void* __restrict__ out,                   // [N,128] fp32|bf16
    const int* __restrict__ flags)
{
    constexpr int K = 128, CH = 16, CAP = 3072;
    __shared__ int sidx[CAP];
    __shared__ int srp[17];
    const int tid = threadIdx.x;
    const int m0 = blockIdx.x * 16;
    if (tid < 17) srp[tid] = rowptr[m0 + tid];
    __syncthreads();
    const int base = srp[0];
    const int total = srp[16] - base;
    const bool staged = total <= CAP;
    if (staged) {
        for (int i = tid; i < total; i += 256) sidx[i] = csr_src[base + i];
    }
    __syncthreads();

    const int rr = tid >> 4;                  // 16 rows
    const int cc = tid & 15;                  // 16 chunks
    const int beg = srp[rr];
    const int deg = srp[rr + 1] - beg;
    const int begl = beg - base;
    float a[8], g[8];
#pragma unroll
    for (int v = 0; v < 8; ++v) { a[v] = 0.f; g[v] = 0.f; }
    const unsigned short* col = hl2 + cc * 8;
    auto run = [&](auto IDX) {
        int j = 0;
        for (; j + 3 < deg; j += 4) {
            int s0 = IDX(j), s1 = IDX(j + 1), s2 = IDX(j + 2), s3 = IDX(j + 3);
            uint4 v0 = *(const uint4*)(col + (size_t)s0 * K);
            uint4 v1 = *(const uint4*)(col + (size_t)s1 * K);
            uint4 v2 = *(const uint4*)(col + (size_t)s2 * K);
            uint4 v3 = *(const uint4*)(col + (size_t)s3 * K);
            acc8(a, v0); acc8(g, v1); acc8(a, v2); acc8(g, v3);
        }
        for (; j < deg; ++j) {
            uint4 v0 = *(const uint4*)(col + (size_t)IDX(j) * K);
            acc8(a, v0);
        }
    };
    if (staged) run([&](int j) { return sidx[begl + j]; });
    else        run([&](int j) { return csr_src[beg + j]; });

    const float inv = 1.0f / fmaxf((float)deg, 1.0f);
    const size_t ro = (size_t)(m0 + rr) * K + cc * 8;
    uint4 hv = *(const uint4*)(hr2 + ro);
    uint4 bv = *(const uint4*)(bb + cc * 8);
    float r8[8], h8[8], b8[8];
    acc8(r8, hv);  // r8 currently garbage-init? no: fill below properly
    // (acc8 adds; initialize instead)
    h8[0] = bfbits2f(hv.x & 0xffffu); h8[1] = bfbits2f(hv.x >> 16);
    h8[2] = bfbits2f(hv.y & 0xffffu); h8[3] = bfbits2f(hv.y >> 16);
    h8[4] = bfbits2f(hv.z & 0xffffu); h8[5] = bfbits2f(hv.z >> 16);
    h8[6] = bfbits2f(hv.w & 0xffffu); h8[7] = bfbits2f(hv.w >> 16);
    b8[0] = bfbits2f(bv.x & 0xffffu); b8[1] = bfbits2f(bv.x >> 16);
    b8[2] = bfbits2f(bv.y & 0xffffu); b8[3] = bfbits2f(bv.y >> 16);
    b8[4] = bfbits2f(bv.z & 0xffffu); b8[5] = bfbits2f(bv.z >> 16);
    b8[6] = bfbits2f(bv.w & 0xffffu); b8[7] = bfbits2f(bv.w >> 16);
    float o8[8];
#pragma unroll
    for (int v = 0; v < 8; ++v) {
        float m = (a[v] + g[v]) * inv + b8[v] + h8[v];
        o8[v] = m > 0.f ? m : 0.f;
    }
    if (flags[0]) {
        float* op = (float*)out + ro;
        float4 o0 = { o8[0], o8[1], o8[2], o8[3] };
        float4 o1 = { o8[4], o8[5], o8[6], o8[7] };
        *(float4*)op = o0;
        *(float4*)(op + 4) = o1;
    } else {
        short8 t8;
#pragma unroll
        for (int v = 0; v < 8; ++v) t8[v] = (short)f2bfbits(o8[v]);
        *(short8*)((unsigned short*)out + ro) = t8;
    }
}

// ---------------- orchestration ----------------
extern "C" void kernel_launch(void* const* d_in, const int* in_sizes, int n_in,
                              void* d_out, int out_size, void* d_ws, size_t ws_size,
                              hipStream_t stream) {
    const void* x  = d_in[0];
    const int* e[3] = { (const int*)d_in[1], (const int*)d_in[2], (const int*)d_in[3] };

    char* ws = (char*)d_ws;
    int* flags = (int*)ws;                                    // @0
    unsigned short* wt = (unsigned short*)(ws + 1024);        // 525,568 B
    unsigned short* bb0 = wt + 262144;
    unsigned short* bb1 = wt + 262400;
    unsigned short* bb2 = wt + 262656;
    int* cnt  = (int*)(ws + 526592);                          // 200,000 B
    int* rp   = (int*)(ws + 726592);                          // 200,004 B
    int* cur  = (int*)(ws + 926596);                          // 200,000 B
    int* part = (int*)(ws + 1126596);                         // 784 B
    int* csr  = (int*)(ws + 1127392);                         // 3.2 MB
    unsigned short* hA = (unsigned short*)(ws + 4327392);     // 25.6 MB
    unsigned short* hB = (unsigned short*)(ws + 29927392);    // 25.6 MB
    // overlays (lifetime-disjoint, total stays 55.5 MB):
    unsigned short* xb  = hB;                 // x as bf16 [N,128] = 12.8 MB; dead once gemm of L1 writes hB
    unsigned short* hl2 = hA;                 // [N,128] 12.8 MB; hA dead after L1 fused reads it
    unsigned short* hr2 = hA + (size_t)N_NODES * 128;

    detect<<<1, 256, 0, stream>>>((const unsigned short*)x, e[0], flags);
    prep_all<<<1027, 256, 0, stream>>>(d_in[4], d_in[6], d_in[7], d_in[9],
                                       d_in[10], d_in[12], d_in[5], d_in[8], d_in[11],
                                       wt, flags);
    cvt_x<<<6250, 256, 0, stream>>>(x, xb, flags);            // N*128/4 threads

    const int EG = N_EDGES / 256;     // 3125
    const int MG = N_NODES / 16;      // 3125

    // ---- layer 0: xb[.,128] -> hA[.,256] ----
    zero_cnt<<<NBLK, 256, 0, stream>>>(cnt);
    edge_count<<<EG, 256, 0, stream>>>(e[0], cnt, flags);
    scan_k1<<<NBLK, 256, 0, stream>>>(cnt, rp, part);
    scan_k2<<<1, 256, 0, stream>>>(part);
    scan_k3<<<NBLK, 256, 0, stream>>>(rp, part, cur);
    edge_fill<<<EG, 256, 0, stream>>>(e[0], cur, csr, flags);
    sage_fused<128><<<MG, 256, 0, stream>>>(xb, rp, csr, wt, wt + 32768, bb0, hA);

    // ---- layer 1: hA[.,256] -> hB[.,256] (clobbers xb — xb dead) ----
    zero_cnt<<<NBLK, 256, 0, stream>>>(cnt);
    edge_count<<<EG, 256, 0, stream>>>(e[1], cnt, flags);
    scan_k1<<<NBLK, 256, 0, stream>>>(cnt, rp, part);
    scan_k2<<<1, 256, 0, stream>>>(part);
    scan_k3<<<NBLK, 256, 0, stream>>>(rp, part, cur);
    edge_fill<<<EG, 256, 0, stream>>>(e[1], cur, csr, flags);
    sage_fused<256><<<MG, 256, 0, stream>>>(hA, rp, csr, wt + 65536, wt + 131072, bb1, hB);

    // ---- layer 2 (reordered): hl2 = hB@Wl2, hr2 = hB@Wr2; out = relu(mean(hl2)+b2+hr2) ----
    zero_cnt<<<NBLK, 256, 0, stream>>>(cnt);
    edge_count<<<EG, 256, 0, stream>>>(e[2], cnt, flags);
    scan_k1<<<NBLK, 256, 0, stream>>>(cnt, rp, part);
    scan_k2<<<1, 256, 0, stream>>>(part);
    scan_k3<<<NBLK, 256, 0, stream>>>(rp, part, cur);
    edge_fill<<<EG, 256, 0, stream>>>(e[2], cur, csr, flags);
    gemm_pair<<<MG, 256, 0, stream>>>(hB, wt + 196608, hl2, hr2);   // writes over dead hA
    agg2<<<MG, 256, 0, stream>>>(hl2, hr2, rp, csr, bb2, d_out, flags);
}